// Round 6
// baseline (3580.009 us; speedup 1.0000x reference)
//
#include <hip/hip_runtime.h>
#include <hip/hip_bf16.h>

typedef _Float16 f16;
typedef _Float16 half8 __attribute__((ext_vector_type(8)));
typedef float f32x4 __attribute__((ext_vector_type(4)));
typedef int i32x4 __attribute__((ext_vector_type(4)));

// B=32, S=1024, D=256, H=256, 4H=1024
// Scan split: cols 0-511 via i8 MFMA (waves 0-7), cols 512-1023 via sdot4
// (waves 8-15). Gates on waves 8-11. h int8 in LDS, exact i32 accumulation.

// ---------------- prep: per-column int8 quantization of U, two layouts ------
// UQd (dot layout, all cols):   dword (dir*1024+c)*64 + kk packs k=4kk..4kk+3
// UQm (mfma layout, cols<512):  uint4 idx ((dir*32+tile)*4+ks)*64 + kg*16+colr
//                               packs k = ks*64 + kg*16 + e (e=0..15), col c
__global__ void prep_uq_kernel(const float* __restrict__ Uf, const float* __restrict__ Ur,
                               unsigned int* __restrict__ UQd, unsigned int* __restrict__ UQm,
                               float* __restrict__ Uscale)
{
    int idx = blockIdx.x * 256 + threadIdx.x;   // (dir, c)
    if (idx >= 2048) return;
    int dir = idx >> 10, c = idx & 1023;
    const float* U = dir ? Ur : Uf;
    float m = 0.f;
    for (int k = 0; k < 256; ++k) m = fmaxf(m, fabsf(U[k * 1024 + c]));
    float sinv = (m > 0.f) ? 127.f / m : 0.f;
    // dot layout
    for (int kk = 0; kk < 64; ++kk) {
        unsigned int w = 0;
        #pragma unroll
        for (int e = 0; e < 4; ++e) {
            int q = __float2int_rn(U[(kk * 4 + e) * 1024 + c] * sinv);
            w |= ((unsigned int)(q & 0xff)) << (8 * e);
        }
        UQd[((size_t)(dir * 1024 + c)) * 64 + kk] = w;
    }
    // mfma layout (cols < 512)
    if (c < 512) {
        int tile = c >> 4, colr = c & 15;
        uint4* UQm4 = (uint4*)UQm;
        for (int ks = 0; ks < 4; ++ks) {
            #pragma unroll
            for (int kg = 0; kg < 4; ++kg) {
                unsigned int w[4];
                #pragma unroll
                for (int d = 0; d < 4; ++d) {
                    unsigned int wd = 0;
                    #pragma unroll
                    for (int e = 0; e < 4; ++e) {
                        int k = ks * 64 + kg * 16 + d * 4 + e;
                        int q = __float2int_rn(U[k * 1024 + c] * sinv);
                        wd |= ((unsigned int)(q & 0xff)) << (8 * e);
                    }
                    w[d] = wd;
                }
                UQm4[((size_t)((dir * 32 + tile) * 4 + ks)) * 64 + kg * 16 + colr] =
                    make_uint4(w[0], w[1], w[2], w[3]);
            }
        }
    }
    Uscale[idx] = m / (127.f * 127.f);
}

// ---------------- projection GEMM (unchanged, proven) -----------------------
__global__ __launch_bounds__(256) void proj_gemm_kernel(
    const float* __restrict__ x, const float* __restrict__ Wf, const float* __restrict__ Wr,
    const float* __restrict__ bfw, const float* __restrict__ brw, f16* __restrict__ G)
{
    const int nt = blockIdx.x;
    const int mt = blockIdx.y;
    const int m0 = mt * 128, n0 = nt * 128;
    const int dir = n0 >> 10, nin0 = n0 & 1023;
    const float* W   = dir ? Wr : Wf;
    const float* bia = dir ? brw : bfw;
    __shared__ f16 Asm[128][40];
    __shared__ f16 Bsm[128][40];
    const int t = threadIdx.x;
    const int lane = t & 63, wave = t >> 6;
    const int wr = wave >> 1, wc = wave & 1;
    f32x4 acc[4][4] = {};
    for (int k0 = 0; k0 < 256; k0 += 32) {
        #pragma unroll
        for (int e = 0; e < 16; ++e) {
            int idx = e * 256 + t;
            int r = idx >> 5, kk = idx & 31;
            Asm[r][kk] = (f16)x[(size_t)(m0 + r) * 256 + (k0 + kk)];
        }
        #pragma unroll
        for (int e = 0; e < 16; ++e) {
            int idx = e * 256 + t;
            int col = idx & 127, kr = idx >> 7;
            Bsm[col][kr] = (f16)W[(size_t)(k0 + kr) * 1024 + (nin0 + col)];
        }
        __syncthreads();
        const int l15 = lane & 15, kb = (lane >> 4) * 8;
        half8 af[4], bfr[4];
        #pragma unroll
        for (int fr = 0; fr < 4; ++fr) af[fr]  = *(const half8*)&Asm[wr * 64 + fr * 16 + l15][kb];
        #pragma unroll
        for (int fc = 0; fc < 4; ++fc) bfr[fc] = *(const half8*)&Bsm[wc * 64 + fc * 16 + l15][kb];
        #pragma unroll
        for (int fr = 0; fr < 4; ++fr)
            #pragma unroll
            for (int fc = 0; fc < 4; ++fc)
                acc[fr][fc] = __builtin_amdgcn_mfma_f32_16x16x32_f16(af[fr], bfr[fc], acc[fr][fc], 0, 0, 0);
        __syncthreads();
    }
    const int row4 = (lane >> 4) * 4, c15 = lane & 15;
    #pragma unroll
    for (int fr = 0; fr < 4; ++fr)
        #pragma unroll
        for (int fc = 0; fc < 4; ++fc) {
            int rbase = m0 + wr * 64 + fr * 16 + row4;
            int cidx  = n0 + wc * 64 + fc * 16 + c15;
            float bv = bia[cidx & 1023];
            #pragma unroll
            for (int i = 0; i < 4; ++i)
                G[(size_t)(rbase + i) * 2048 + cidx] = (f16)(acc[fr][fc][i] + bv);
        }
}

// ---------------- scan ------------------------------------------------------
__device__ __forceinline__ int dot4i8(unsigned int a, unsigned int b, int c) {
#if __has_builtin(__builtin_amdgcn_sdot4)
    return __builtin_amdgcn_sdot4(a, b, c, false);
#else
    c += (int)(signed char)(a)       * (int)(signed char)(b);
    c += (int)(signed char)(a >> 8)  * (int)(signed char)(b >> 8);
    c += (int)(signed char)(a >> 16) * (int)(signed char)(b >> 16);
    c += (int)(signed char)(a >> 24) * (int)(signed char)(b >> 24);
    return c;
#endif
}

__device__ __forceinline__ float tanh_fast(float x) {
    float e = __expf(2.f * x);
    return 1.f - 2.f / (e + 1.f);
}

__global__
__attribute__((amdgpu_flat_work_group_size(1024, 1024)))
void scan_kernel(
    const f16* __restrict__ G, const unsigned int* __restrict__ UQd,
    const unsigned int* __restrict__ UQm, const float* __restrict__ Uscale,
    float* __restrict__ out)
{
    const int wg = blockIdx.x;
    const int dir = wg >> 5, b = wg & 31;
    const int tid = threadIdx.x;
    const int wave = tid >> 6, lane = tid & 63;
    const bool is_dot  = (tid >= 512);          // waves 8-15: dot4, cols 512-1023
    const bool is_gate = (tid >= 512 && tid < 768);  // waves 8-11: gate phase
    const int gc = tid & 255;                   // gate column base (gates only)

    __shared__ __align__(16) unsigned int hq[64];   // h int8[256]
    __shared__ float pre[1024];                     // scaled recurrent term

    if (tid < 64) hq[tid] = 0u;

    // gate-thread state: xW for cols gc + 256j, prefetched
    const f16* Grow = G + (size_t)b * 1024 * 2048 + dir * 1024 + gc;
    float* outp = out + (size_t)b * 1024 * 512 + dir * 256 + gc;
    float xwc0 = 0.f, xwc1 = 0.f, xwc2 = 0.f, xwc3 = 0.f;
    float c_state = 0.f;
    const int s0 = dir ? 1023 : 0;
    if (is_gate) {
        xwc0 = (float)Grow[(size_t)s0 * 2048 + 0];
        xwc1 = (float)Grow[(size_t)s0 * 2048 + 256];
        xwc2 = (float)Grow[(size_t)s0 * 2048 + 512];
        xwc3 = (float)Grow[(size_t)s0 * 2048 + 768];
    }

    // dot-path init: U column tid resident (asm defs, same as r5)
    uint4 ureg[16];
    float usc = 0.f;
    // mfma-path init: B-fragments for 4 tiles x 4 K-steps (64 regs; AGPR ok)
    i32x4 uf[4][4];
    float usc4[4] = {0.f, 0.f, 0.f, 0.f};

    if (is_dot) {
        const uint4* up = (const uint4*)(UQd + ((size_t)(dir * 1024 + tid)) * 64);
        #pragma unroll
        for (int kkk = 0; kkk < 16; ++kkk)
            asm volatile("global_load_dwordx4 %0, %1, off offset:%2"
                         : "=v"(ureg[kkk]) : "v"(up), "i"(kkk * 16));
        asm volatile("s_waitcnt vmcnt(0)" ::: "memory");
        __builtin_amdgcn_sched_barrier(0);
        usc = Uscale[dir * 1024 + tid];
    } else {
        const i32x4* UQm4 = (const i32x4*)UQm;
        #pragma unroll
        for (int tau = 0; tau < 4; ++tau)
            #pragma unroll
            for (int ks = 0; ks < 4; ++ks)
                uf[tau][ks] = UQm4[((size_t)((dir * 32 + wave * 4 + tau) * 4 + ks)) * 64 + lane];
        if (lane < 16) {
            #pragma unroll
            for (int tau = 0; tau < 4; ++tau)
                usc4[tau] = Uscale[dir * 1024 + wave * 64 + tau * 16 + lane];
        }
    }
    __syncthreads();

    const uint4* hp4 = (const uint4*)hq;
    const char* hqb = (const char*)hq;

    for (int t = 0; t < 1024; ++t) {
        const int s  = dir ? (1023 - t) : t;
        const int tn = (t < 1023) ? (t + 1) : t;
        const int sn = dir ? (1023 - tn) : tn;

        f16 xn0, xn1, xn2, xn3;
        if (is_gate) {                          // prefetch next step's xW
            xn0 = Grow[(size_t)sn * 2048 + 0];
            xn1 = Grow[(size_t)sn * 2048 + 256];
            xn2 = Grow[(size_t)sn * 2048 + 512];
            xn3 = Grow[(size_t)sn * 2048 + 768];
        }

        if (is_dot) {
            int i0 = 0, i1 = 0, i2 = 0, i3 = 0;
            #pragma unroll
            for (int ch = 0; ch < 4; ++ch) {
                uint4 ha = hp4[ch * 4 + 0];
                uint4 hb = hp4[ch * 4 + 1];
                uint4 hc = hp4[ch * 4 + 2];
                uint4 hd = hp4[ch * 4 + 3];
                i0 = dot4i8(ureg[ch * 4 + 0].x, ha.x, i0);
                i1 = dot4i8(ureg[ch * 4 + 0].y, ha.y, i1);
                i2 = dot4i8(ureg[ch * 4 + 0].z, ha.z, i2);
                i3 = dot4i8(ureg[ch * 4 + 0].w, ha.w, i3);
                i0 = dot4i8(ureg[ch * 4 + 1].x, hb.x, i0);
                i1 = dot4i8(ureg[ch * 4 + 1].y, hb.y, i1);
                i2 = dot4i8(ureg[ch * 4 + 1].z, hb.z, i2);
                i3 = dot4i8(ureg[ch * 4 + 1].w, hb.w, i3);
                i0 = dot4i8(ureg[ch * 4 + 2].x, hc.x, i0);
                i1 = dot4i8(ureg[ch * 4 + 2].y, hc.y, i1);
                i2 = dot4i8(ureg[ch * 4 + 2].z, hc.z, i2);
                i3 = dot4i8(ureg[ch * 4 + 2].w, hc.w, i3);
                i0 = dot4i8(ureg[ch * 4 + 3].x, hd.x, i0);
                i1 = dot4i8(ureg[ch * 4 + 3].y, hd.y, i1);
                i2 = dot4i8(ureg[ch * 4 + 3].z, hd.z, i2);
                i3 = dot4i8(ureg[ch * 4 + 3].w, hd.w, i3);
                __builtin_amdgcn_sched_barrier(0);
            }
            int iacc = (i0 + i1) + (i2 + i3);
            pre[tid] = (float)iacc * usc;
        } else {
            // MFMA half: preact[cols wave*64 .. +63] = h @ U (i8, exact i32)
            // A = h broadcast across all 16 rows (address indep of lane&15),
            // so any C row is the result; use row 0 (lanes 0-15, reg 0).
            i32x4 acc0 = {0,0,0,0}, acc1 = {0,0,0,0}, acc2 = {0,0,0,0}, acc3 = {0,0,0,0};
            #pragma unroll
            for (int ks = 0; ks < 4; ++ks) {
                i32x4 a = *(const i32x4*)(hqb + ks * 64 + ((lane >> 4) << 4));
                acc0 = __builtin_amdgcn_mfma_i32_16x16x64_i8(a, uf[0][ks], acc0, 0, 0, 0);
                acc1 = __builtin_amdgcn_mfma_i32_16x16x64_i8(a, uf[1][ks], acc1, 0, 0, 0);
                acc2 = __builtin_amdgcn_mfma_i32_16x16x64_i8(a, uf[2][ks], acc2, 0, 0, 0);
                acc3 = __builtin_amdgcn_mfma_i32_16x16x64_i8(a, uf[3][ks], acc3, 0, 0, 0);
            }
            if (lane < 16) {
                pre[wave * 64 +  0 + lane] = (float)acc0[0] * usc4[0];
                pre[wave * 64 + 16 + lane] = (float)acc1[0] * usc4[1];
                pre[wave * 64 + 32 + lane] = (float)acc2[0] * usc4[2];
                pre[wave * 64 + 48 + lane] = (float)acc3[0] * usc4[3];
            }
        }
        __syncthreads();

        if (is_gate) {
            float pi = pre[gc      ] + xwc0;
            float pf = pre[gc + 256] + xwc1;
            float pg = pre[gc + 512] + xwc2;
            float po = pre[gc + 768] + xwc3;
            float ig = 1.f / (1.f + __expf(-pi));
            float fg = 1.f / (1.f + __expf(-pf));
            float gg = tanh_fast(pg);
            float og = 1.f / (1.f + __expf(-po));
            c_state = fg * c_state + ig * gg;
            float h = og * tanh_fast(c_state);
            outp[(size_t)s * 512] = h;
            ((signed char*)hq)[gc] = (signed char)__float2int_rn(h * 127.f);
            xwc0 = (float)xn0; xwc1 = (float)xn1; xwc2 = (float)xn2; xwc3 = (float)xn3;
        }
        __syncthreads();
    }
}

extern "C" void kernel_launch(void* const* d_in, const int* in_sizes, int n_in,
                              void* d_out, int out_size, void* d_ws, size_t ws_size,
                              hipStream_t stream) {
    const float* x  = (const float*)d_in[0];
    const float* Wf = (const float*)d_in[1];
    const float* Uf = (const float*)d_in[2];
    const float* bf = (const float*)d_in[3];
    const float* Wr = (const float*)d_in[4];
    const float* Ur = (const float*)d_in[5];
    const float* br = (const float*)d_in[6];
    float* out = (float*)d_out;

    char* ws = (char*)d_ws;
    unsigned int* UQd = (unsigned int*)ws;                      // 512 KB @ 0
    float* Uscale     = (float*)(ws + (size_t)512 * 1024);      // 8 KB
    unsigned int* UQm = (unsigned int*)(ws + (size_t)768 * 1024); // 256 KB
    f16* G            = (f16*)(ws + (size_t)1024 * 1024);       // 128 MB

    prep_uq_kernel<<<8, 256, 0, stream>>>(Uf, Ur, UQd, UQm, Uscale);
    dim3 gg(16, 256);
    proj_gemm_kernel<<<gg, 256, 0, stream>>>(x, Wf, Wr, bf, br, G);
    scan_kernel<<<64, 1024, 0, stream>>>(G, UQd, UQm, Uscale, out);
}

// Round 7
// 1053.914 us; speedup vs baseline: 3.3969x; 3.3969x over previous
//
#include <hip/hip_runtime.h>
#include <hip/hip_bf16.h>

typedef _Float16 f16;
typedef _Float16 half8 __attribute__((ext_vector_type(8)));
typedef float f32x4 __attribute__((ext_vector_type(4)));
typedef int i32x4 __attribute__((ext_vector_type(4)));

// B=32, S=1024, D=256, H=256, 4H=1024
// Scan: ALL 1024 gate cols via i8 MFMA (layout HW-verified in r6).
// 64 WGs = (dir,b), 16 waves; wave w owns cols [w*64, w*64+64) = tiles w*4..w*4+3.

// ---------------- prep: per-column int8 quantization of U (mfma layout) -----
// UQm uint4 index: ((dir*64 + tile)*4 + ks)*64 + kg*16 + colr
//   holds k = ks*64 + kg*16 + {0..15} (16 int8) for col = tile*16 + colr.
//   Lane l reads ... + l -> kg = l>>4, colr = l&15 (B-fragment mapping, r6-verified).
__global__ void prep_uq_kernel(const float* __restrict__ Uf, const float* __restrict__ Ur,
                               unsigned int* __restrict__ UQm, float* __restrict__ Uscale)
{
    int idx = blockIdx.x * 256 + threadIdx.x;   // (dir, c)
    if (idx >= 2048) return;
    int dir = idx >> 10, c = idx & 1023;
    const float* U = dir ? Ur : Uf;
    float m = 0.f;
    for (int k = 0; k < 256; ++k) m = fmaxf(m, fabsf(U[k * 1024 + c]));
    float sinv = (m > 0.f) ? 127.f / m : 0.f;
    int tile = c >> 4, colr = c & 15;
    uint4* UQm4 = (uint4*)UQm;
    for (int ks = 0; ks < 4; ++ks) {
        #pragma unroll
        for (int kg = 0; kg < 4; ++kg) {
            unsigned int w[4];
            #pragma unroll
            for (int d = 0; d < 4; ++d) {
                unsigned int wd = 0;
                #pragma unroll
                for (int e = 0; e < 4; ++e) {
                    int k = ks * 64 + kg * 16 + d * 4 + e;
                    int q = __float2int_rn(U[k * 1024 + c] * sinv);
                    wd |= ((unsigned int)(q & 0xff)) << (8 * e);
                }
                w[d] = wd;
            }
            UQm4[((size_t)((dir * 64 + tile) * 4 + ks)) * 64 + kg * 16 + colr] =
                make_uint4(w[0], w[1], w[2], w[3]);
        }
    }
    Uscale[idx] = m / (127.f * 127.f);  // U-scale * h-dequant(1/127)
}

// ---------------- projection GEMM (unchanged, proven) -----------------------
__global__ __launch_bounds__(256) void proj_gemm_kernel(
    const float* __restrict__ x, const float* __restrict__ Wf, const float* __restrict__ Wr,
    const float* __restrict__ bfw, const float* __restrict__ brw, f16* __restrict__ G)
{
    const int nt = blockIdx.x;
    const int mt = blockIdx.y;
    const int m0 = mt * 128, n0 = nt * 128;
    const int dir = n0 >> 10, nin0 = n0 & 1023;
    const float* W   = dir ? Wr : Wf;
    const float* bia = dir ? brw : bfw;
    __shared__ f16 Asm[128][40];
    __shared__ f16 Bsm[128][40];
    const int t = threadIdx.x;
    const int lane = t & 63, wave = t >> 6;
    const int wr = wave >> 1, wc = wave & 1;
    f32x4 acc[4][4] = {};
    for (int k0 = 0; k0 < 256; k0 += 32) {
        #pragma unroll
        for (int e = 0; e < 16; ++e) {
            int idx = e * 256 + t;
            int r = idx >> 5, kk = idx & 31;
            Asm[r][kk] = (f16)x[(size_t)(m0 + r) * 256 + (k0 + kk)];
        }
        #pragma unroll
        for (int e = 0; e < 16; ++e) {
            int idx = e * 256 + t;
            int col = idx & 127, kr = idx >> 7;
            Bsm[col][kr] = (f16)W[(size_t)(k0 + kr) * 1024 + (nin0 + col)];
        }
        __syncthreads();
        const int l15 = lane & 15, kb = (lane >> 4) * 8;
        half8 af[4], bfr[4];
        #pragma unroll
        for (int fr = 0; fr < 4; ++fr) af[fr]  = *(const half8*)&Asm[wr * 64 + fr * 16 + l15][kb];
        #pragma unroll
        for (int fc = 0; fc < 4; ++fc) bfr[fc] = *(const half8*)&Bsm[wc * 64 + fc * 16 + l15][kb];
        #pragma unroll
        for (int fr = 0; fr < 4; ++fr)
            #pragma unroll
            for (int fc = 0; fc < 4; ++fc)
                acc[fr][fc] = __builtin_amdgcn_mfma_f32_16x16x32_f16(af[fr], bfr[fc], acc[fr][fc], 0, 0, 0);
        __syncthreads();
    }
    const int row4 = (lane >> 4) * 4, c15 = lane & 15;
    #pragma unroll
    for (int fr = 0; fr < 4; ++fr)
        #pragma unroll
        for (int fc = 0; fc < 4; ++fc) {
            int rbase = m0 + wr * 64 + fr * 16 + row4;
            int cidx  = n0 + wc * 64 + fc * 16 + c15;
            float bv = bia[cidx & 1023];
            #pragma unroll
            for (int i = 0; i < 4; ++i)
                G[(size_t)(rbase + i) * 2048 + cidx] = (f16)(acc[fr][fc][i] + bv);
        }
}

// ---------------- scan ------------------------------------------------------
__device__ __forceinline__ float tanh_fast(float x) {
    float e = __expf(2.f * x);
    return 1.f - 2.f / (e + 1.f);
}

// waves_per_eu(4,4): 1024 thr = 16 waves/CU = exactly 4 waves/EU; gives each
// wave a 512-reg unified budget so the 64-reg U B-fragments live in AGPRs
// (MFMA reads AGPRs natively - no move cost, unlike the dot4 path which paid
// one v_accvgpr_read per MAC4). r6 regressed because this attribute was
// missing -> uf spilled to scratch -> per-step reloads (MfmaUtil 1.6%).
__global__
__attribute__((amdgpu_flat_work_group_size(1024, 1024)))
__attribute__((amdgpu_waves_per_eu(4, 4)))
void scan_kernel(
    const f16* __restrict__ G, const unsigned int* __restrict__ UQm,
    const float* __restrict__ Uscale, float* __restrict__ out)
{
    const int wg = blockIdx.x;
    const int dir = wg >> 5, b = wg & 31;
    const int tid = threadIdx.x;
    const int wave = tid >> 6, lane = tid & 63;
    const bool is_gate = (tid < 256);           // waves 0-3 (one per SIMD)
    const int gc = tid & 255;

    __shared__ __align__(16) unsigned int hq[64];   // h int8[256]
    __shared__ float pre[1024];                     // scaled recurrent term

    if (tid < 64) hq[tid] = 0u;

    // B-fragments: 4 tiles x 4 K-steps, i32x4 each = 64 regs -> AGPR resident
    const i32x4* UQm4 = (const i32x4*)UQm;
    i32x4 uf[4][4];
    #pragma unroll
    for (int tau = 0; tau < 4; ++tau)
        #pragma unroll
        for (int ks = 0; ks < 4; ++ks)
            uf[tau][ks] = UQm4[((size_t)((dir * 64 + wave * 4 + tau) * 4 + ks)) * 64 + lane];

    float usc[4] = {0.f, 0.f, 0.f, 0.f};
    if (lane < 16) {
        #pragma unroll
        for (int tau = 0; tau < 4; ++tau)
            usc[tau] = Uscale[dir * 1024 + wave * 64 + tau * 16 + lane];
    }

    // gate-thread state
    const f16* Grow = G + (size_t)b * 1024 * 2048 + dir * 1024 + gc;
    float* outp = out + (size_t)b * 1024 * 512 + dir * 256 + gc;
    float xwc0 = 0.f, xwc1 = 0.f, xwc2 = 0.f, xwc3 = 0.f;
    float c_state = 0.f;
    const int s0 = dir ? 1023 : 0;
    if (is_gate) {
        xwc0 = (float)Grow[(size_t)s0 * 2048 + 0];
        xwc1 = (float)Grow[(size_t)s0 * 2048 + 256];
        xwc2 = (float)Grow[(size_t)s0 * 2048 + 512];
        xwc3 = (float)Grow[(size_t)s0 * 2048 + 768];
    }
    __syncthreads();

    const char* hqb = (const char*)hq;
    const int arow = (lane >> 4) << 4;          // A-fragment byte offset in h

    for (int t = 0; t < 1024; ++t) {
        const int s  = dir ? (1023 - t) : t;
        const int tn = (t < 1023) ? (t + 1) : t;
        const int sn = dir ? (1023 - tn) : tn;

        f16 xn0, xn1, xn2, xn3;
        if (is_gate) {                          // prefetch next step's xW
            xn0 = Grow[(size_t)sn * 2048 + 0];
            xn1 = Grow[(size_t)sn * 2048 + 256];
            xn2 = Grow[(size_t)sn * 2048 + 512];
            xn3 = Grow[(size_t)sn * 2048 + 768];
        }

        // pre[wave*64 + tau*16 + col] = (h @ U)[col] * usc   (exact i32 accum)
        // A = h replicated across the 16 rows (addr indep of lane&15), so
        // every C row holds the result; lanes 0-15 reg 0 = row 0.
        i32x4 acc0 = {0,0,0,0}, acc1 = {0,0,0,0}, acc2 = {0,0,0,0}, acc3 = {0,0,0,0};
        #pragma unroll
        for (int ks = 0; ks < 4; ++ks) {
            i32x4 a = *(const i32x4*)(hqb + ks * 64 + arow);
            acc0 = __builtin_amdgcn_mfma_i32_16x16x64_i8(a, uf[0][ks], acc0, 0, 0, 0);
            acc1 = __builtin_amdgcn_mfma_i32_16x16x64_i8(a, uf[1][ks], acc1, 0, 0, 0);
            acc2 = __builtin_amdgcn_mfma_i32_16x16x64_i8(a, uf[2][ks], acc2, 0, 0, 0);
            acc3 = __builtin_amdgcn_mfma_i32_16x16x64_i8(a, uf[3][ks], acc3, 0, 0, 0);
        }
        if (lane < 16) {
            pre[wave * 64 +  0 + lane] = (float)acc0[0] * usc[0];
            pre[wave * 64 + 16 + lane] = (float)acc1[0] * usc[1];
            pre[wave * 64 + 32 + lane] = (float)acc2[0] * usc[2];
            pre[wave * 64 + 48 + lane] = (float)acc3[0] * usc[3];
        }
        __syncthreads();

        if (is_gate) {
            float pi = pre[gc      ] + xwc0;
            float pf = pre[gc + 256] + xwc1;
            float pg = pre[gc + 512] + xwc2;
            float po = pre[gc + 768] + xwc3;
            float ig = 1.f / (1.f + __expf(-pi));
            float fg = 1.f / (1.f + __expf(-pf));
            float gg = tanh_fast(pg);
            float og = 1.f / (1.f + __expf(-po));
            c_state = fg * c_state + ig * gg;
            float h = og * tanh_fast(c_state);
            outp[(size_t)s * 512] = h;
            ((signed char*)hq)[gc] = (signed char)__float2int_rn(h * 127.f);
            xwc0 = (float)xn0; xwc1 = (float)xn1; xwc2 = (float)xn2; xwc3 = (float)xn3;
        }
        __syncthreads();
    }
}

extern "C" void kernel_launch(void* const* d_in, const int* in_sizes, int n_in,
                              void* d_out, int out_size, void* d_ws, size_t ws_size,
                              hipStream_t stream) {
    const float* x  = (const float*)d_in[0];
    const float* Wf = (const float*)d_in[1];
    const float* Uf = (const float*)d_in[2];
    const float* bf = (const float*)d_in[3];
    const float* Wr = (const float*)d_in[4];
    const float* Ur = (const float*)d_in[5];
    const float* br = (const float*)d_in[6];
    float* out = (float*)d_out;

    char* ws = (char*)d_ws;
    unsigned int* UQm = (unsigned int*)ws;                      // 512 KB
    float* Uscale     = (float*)(ws + (size_t)512 * 1024);      // 8 KB
    f16* G            = (f16*)(ws + (size_t)1024 * 1024);       // 128 MB

    prep_uq_kernel<<<8, 256, 0, stream>>>(Uf, Ur, UQm, Uscale);
    dim3 gg(16, 256);
    proj_gemm_kernel<<<gg, 256, 0, stream>>>(x, Wf, Wr, bf, br, G);
    scan_kernel<<<64, 1024, 0, stream>>>(G, UQm, Uscale, out);
}